// Round 1
// baseline (3101.968 us; speedup 1.0000x reference)
//
#include <hip/hip_runtime.h>
#include <math.h>

#define NN 3136      // H*W = 56*56
#define CC 96
#define BB 8
#define KNB 9
#define FLT_MAX_ 3.402823466e+38f

// ---------------------------------------------------------------------------
// 1x1 conv as batched GEMM: out[b,o,n] = bias[o] + sum_k w[o*K+k] * in[b,k,n]
// Tile: 64 (o) x 64 (n), 256 threads, 4x4 micro-tile, K staged 16 deep in LDS.
// ---------------------------------------------------------------------------
__global__ __launch_bounds__(256) void conv1_kernel(
    const float* __restrict__ in, const float* __restrict__ w,
    const float* __restrict__ bias, float* __restrict__ out, int K, int O)
{
    __shared__ float sW[16][64];   // [kk][o]
    __shared__ float sX[16][64];   // [kk][n]
    const int b  = blockIdx.z;
    const int n0 = blockIdx.x * 64;
    const int o0 = blockIdx.y * 64;
    const int tid = threadIdx.x;
    const int tx = tid & 15, ty = tid >> 4;
    const float* inb = in + (size_t)b * K * NN;

    float acc[4][4] = {{0.f}};

    for (int kb = 0; kb < K; kb += 16) {
        __syncthreads();
        // W tile: each thread loads 4 consecutive k for one o (coalesced in k)
        {
            int o  = tid >> 2;
            int k4 = (tid & 3) << 2;
            float4 wv = make_float4(0.f, 0.f, 0.f, 0.f);
            if (o0 + o < O)
                wv = *(const float4*)&w[(size_t)(o0 + o) * K + kb + k4];
            sW[k4 + 0][o] = wv.x; sW[k4 + 1][o] = wv.y;
            sW[k4 + 2][o] = wv.z; sW[k4 + 3][o] = wv.w;
        }
        // X tile: 1024 elements, coalesced over n
        #pragma unroll
        for (int i = 0; i < 4; i++) {
            int e = tid + i * 256;
            int kk = e >> 6, n2 = e & 63;
            sX[kk][n2] = inb[(size_t)(kb + kk) * NN + n0 + n2];
        }
        __syncthreads();
        #pragma unroll
        for (int kk = 0; kk < 16; kk++) {
            const float4 av = *(const float4*)&sW[kk][ty << 2];
            const float4 xv = *(const float4*)&sX[kk][tx << 2];
            float a_[4] = {av.x, av.y, av.z, av.w};
            float x_[4] = {xv.x, xv.y, xv.z, xv.w};
            #pragma unroll
            for (int i = 0; i < 4; i++)
                #pragma unroll
                for (int j = 0; j < 4; j++)
                    acc[i][j] = fmaf(a_[i], x_[j], acc[i][j]);
        }
    }
    #pragma unroll
    for (int i = 0; i < 4; i++) {
        int o = o0 + (ty << 2) + i;
        if (o < O) {
            float bo = bias[o];
            float4 v = make_float4(acc[i][0] + bo, acc[i][1] + bo,
                                   acc[i][2] + bo, acc[i][3] + bo);
            *(float4*)&out[((size_t)b * O + o) * NN + n0 + (tx << 2)] = v;
        }
    }
}

// ---------------------------------------------------------------------------
// Instance norm over N per (b,c) row, with optional activation and residual.
// act: 0 = none, 1 = exact gelu, 2 = relu
// ---------------------------------------------------------------------------
__global__ __launch_bounds__(256) void inorm_kernel(
    const float* __restrict__ in, float* __restrict__ out,
    const float* __restrict__ res, int act)
{
    const int row = blockIdx.x;                 // b*ch + c
    const float* x = in + (size_t)row * NN;
    const int tid = threadIdx.x;

    float v[13];
    float s = 0.f;
    #pragma unroll
    for (int i = 0; i < 13; i++) {
        int idx = tid + i * 256;
        v[i] = (idx < NN) ? x[idx] : 0.f;
        s += v[i];
    }
    __shared__ float red[4];
    #pragma unroll
    for (int off = 32; off > 0; off >>= 1) s += __shfl_down(s, off);
    if ((tid & 63) == 0) red[tid >> 6] = s;
    __syncthreads();
    const float mean = (red[0] + red[1] + red[2] + red[3]) * (1.f / (float)NN);

    float s2 = 0.f;
    #pragma unroll
    for (int i = 0; i < 13; i++) {
        int idx = tid + i * 256;
        if (idx < NN) { float d = v[i] - mean; s2 = fmaf(d, d, s2); }
    }
    #pragma unroll
    for (int off = 32; off > 0; off >>= 1) s2 += __shfl_down(s2, off);
    __syncthreads();
    if ((tid & 63) == 0) red[tid >> 6] = s2;
    __syncthreads();
    const float var = (red[0] + red[1] + red[2] + red[3]) * (1.f / (float)NN);
    const float rs = rsqrtf(var + 1e-5f);

    float* o = out + (size_t)row * NN;
    const float* rr = res ? (res + (size_t)row * NN) : nullptr;
    #pragma unroll
    for (int i = 0; i < 13; i++) {
        int idx = tid + i * 256;
        if (idx < NN) {
            float y = (v[i] - mean) * rs;
            if (act == 1)      y = 0.5f * y * (1.f + erff(y * 0.70710678118654752f));
            else if (act == 2) y = fmaxf(y, 0.f);
            if (rr) y += rr[idx];
            o[idx] = y;
        }
    }
}

// ---------------------------------------------------------------------------
// Column (channel) L2-normalize: xn[b,c,n] = xf[b,c,n] / max(||xf[b,:,n]||,1e-12)
// Also writes sq[b,n] = sum_c xn^2 (== sq_m term of the distance).
// ---------------------------------------------------------------------------
__global__ __launch_bounds__(256) void colnorm_kernel(
    const float* __restrict__ xf, float* __restrict__ xn,
    float* __restrict__ sqc)
{
    const int g = blockIdx.x * 256 + threadIdx.x;   // over B*N
    const int b = g / NN;
    const int n = g - b * NN;
    const float* p = xf + (size_t)b * CC * NN + n;
    float* q = xn + (size_t)b * CC * NN + n;

    float s = 0.f;
    for (int c = 0; c < CC; c++) { float t = p[(size_t)c * NN]; s = fmaf(t, t, s); }
    const float den = fmaxf(sqrtf(s), 1e-12f);

    float sq = 0.f;
    for (int c = 0; c < CC; c++) {
        float t = p[(size_t)c * NN] / den;
        q[(size_t)c * NN] = t;
        sq = fmaf(t, t, sq);
    }
    sqc[g] = sq;
}

// ---------------------------------------------------------------------------
// kNN: for each (b,row) find indices of the 9 smallest
//   d[m] = sq[m] - 2*dot(xn[:,row], xn[:,m]) + rp[row,m]
// (sq[row] dropped: constant per row, ranking-invariant.)
// Block: 64 rows x all 3136 cols; 256 threads, 4x4 micro-tile GEMM;
// per-thread sorted top-9 (registers, fully unrolled), LDS merge at end.
// ---------------------------------------------------------------------------
__global__ __launch_bounds__(256) void knn_kernel(
    const float* __restrict__ xn, const float* __restrict__ sqc,
    const float* __restrict__ rp, int* __restrict__ nn_idx)
{
    __shared__ float shR[CC * 64];   // [c][r]
    __shared__ float shC[CC * 64];   // [c][m]
    const int b  = blockIdx.y;
    const int r0 = blockIdx.x * 64;
    const int tid = threadIdx.x;
    const int tx = tid & 15, ty = tid >> 4;
    const float* xb = xn + (size_t)b * CC * NN;

    for (int e = tid; e < CC * 64; e += 256) {
        int c = e >> 6, r = e & 63;
        shR[e] = xb[(size_t)c * NN + r0 + r];
    }

    float dval[4][9]; int didx[4][9];
    #pragma unroll
    for (int i = 0; i < 4; i++)
        #pragma unroll
        for (int j = 0; j < 9; j++) { dval[i][j] = FLT_MAX_; didx[i][j] = 0x7fffffff; }

    for (int mt = 0; mt < NN / 64; mt++) {
        const int m0 = mt * 64;
        __syncthreads();
        for (int e = tid; e < CC * 64; e += 256) {
            int c = e >> 6, m = e & 63;
            shC[e] = xb[(size_t)c * NN + m0 + m];
        }
        __syncthreads();

        float acc[4][4] = {{0.f}};
        for (int c = 0; c < CC; c++) {
            const float4 rv = *(const float4*)&shR[c * 64 + (ty << 2)];
            const float4 cv = *(const float4*)&shC[c * 64 + (tx << 2)];
            float r_[4] = {rv.x, rv.y, rv.z, rv.w};
            float c_[4] = {cv.x, cv.y, cv.z, cv.w};
            #pragma unroll
            for (int i = 0; i < 4; i++)
                #pragma unroll
                for (int j = 0; j < 4; j++)
                    acc[i][j] = fmaf(r_[i], c_[j], acc[i][j]);
        }

        const float4 sv = *(const float4*)&sqc[(size_t)b * NN + m0 + (tx << 2)];
        const float sq_[4] = {sv.x, sv.y, sv.z, sv.w};
        #pragma unroll
        for (int i = 0; i < 4; i++) {
            const int r = r0 + (ty << 2) + i;
            const float4 rpv = *(const float4*)&rp[(size_t)r * NN + m0 + (tx << 2)];
            const float rp_[4] = {rpv.x, rpv.y, rpv.z, rpv.w};
            #pragma unroll
            for (int j = 0; j < 4; j++) {
                float d = fmaf(-2.f, acc[i][j], sq_[j] + rp_[j]);
                int   m = m0 + (tx << 2) + j;
                if (d < dval[i][8]) {
                    dval[i][8] = d; didx[i][8] = m;
                    #pragma unroll
                    for (int j2 = 8; j2 > 0; --j2) {
                        if (dval[i][j2] < dval[i][j2 - 1]) {
                            float tv = dval[i][j2]; dval[i][j2] = dval[i][j2 - 1]; dval[i][j2 - 1] = tv;
                            int   ti = didx[i][j2]; didx[i][j2] = didx[i][j2 - 1]; didx[i][j2 - 1] = ti;
                        }
                    }
                }
            }
        }
    }

    // merge 16 partial lists per row through LDS (overlay on shR)
    float* mv = shR;
    int*   mi = (int*)(shR + 256 * KNB);
    for (int i = 0; i < 4; i++) {
        __syncthreads();
        #pragma unroll
        for (int j = 0; j < 9; j++) { mv[tid * 9 + j] = dval[i][j]; mi[tid * 9 + j] = didx[i][j]; }
        __syncthreads();
        if (tid < 16) {
            const int ty2 = tid;
            float bv[9]; int bi[9];
            #pragma unroll
            for (int j = 0; j < 9; j++) { bv[j] = FLT_MAX_; bi[j] = 0x7fffffff; }
            for (int t = 0; t < 16; t++) {
                const int base = (ty2 * 16 + t) * 9;
                #pragma unroll
                for (int j = 0; j < 9; j++) {
                    float d = mv[base + j]; int m = mi[base + j];
                    bool ins = (d < bv[8]) || (d == bv[8] && m < bi[8]);
                    if (ins) {
                        bv[8] = d; bi[8] = m;
                        #pragma unroll
                        for (int j2 = 8; j2 > 0; --j2) {
                            bool sw = (bv[j2] < bv[j2 - 1]) ||
                                      (bv[j2] == bv[j2 - 1] && bi[j2] < bi[j2 - 1]);
                            if (sw) {
                                float tv = bv[j2]; bv[j2] = bv[j2 - 1]; bv[j2 - 1] = tv;
                                int   ti = bi[j2]; bi[j2] = bi[j2 - 1]; bi[j2 - 1] = ti;
                            }
                        }
                    }
                }
            }
            const int r = r0 + ty2 * 4 + i;
            #pragma unroll
            for (int j = 0; j < 9; j++)
                nn_idx[((size_t)b * NN + r) * KNB + j] = bi[j];
        }
    }
}

// ---------------------------------------------------------------------------
// Max-relative gather + channel interleave:
// y[b,2c,n] = xf[b,c,n]; y[b,2c+1,n] = max_k( xf[b,c,idx[b,n,k]] - xf[b,c,n] )
// ---------------------------------------------------------------------------
__global__ __launch_bounds__(256) void gather_kernel(
    const float* __restrict__ xf, const int* __restrict__ nn_idx,
    float* __restrict__ y)
{
    const size_t g = (size_t)blockIdx.x * 256 + threadIdx.x;   // over B*C*N
    const int n  = (int)(g % NN);
    const int bc = (int)(g / NN);
    const int c  = bc % CC;
    const int b  = bc / CC;
    const float* row = xf + (size_t)(b * CC + c) * NN;
    const float xi = row[n];
    const int* id = nn_idx + ((size_t)b * NN + n) * KNB;
    float mx = -FLT_MAX_;
    #pragma unroll
    for (int k = 0; k < KNB; k++) mx = fmaxf(mx, row[id[k]] - xi);
    float* o = y + ((size_t)b * 2 * CC + 2 * c) * NN + n;
    o[0]  = xi;
    o[NN] = mx;
}

// ---------------------------------------------------------------------------
// Host-side orchestration
// ---------------------------------------------------------------------------
static void conv1(const float* in, const float* w, const float* b, float* out,
                  int K, int O, hipStream_t s)
{
    dim3 grid(NN / 64, (O + 63) / 64, BB);
    conv1_kernel<<<grid, 256, 0, s>>>(in, w, b, out, K, O);
}
static void inorm(const float* in, float* out, const float* res, int ch, int act,
                  hipStream_t s)
{
    inorm_kernel<<<BB * ch, 256, 0, s>>>(in, out, res, act);
}

struct GrapherP {
    const float *fc1w, *fc1b, *mrw, *mrb, *fc2w, *fc2b;
};

static void run_grapher(const float* in, const float* rp, const GrapherP& p,
                        float* outCur, float* bufA, float* bufB, float* xnb,
                        float* sqc, int* idx, hipStream_t s)
{
    conv1(in, p.fc1w, p.fc1b, bufA, CC, CC, s);
    inorm(bufA, bufB, nullptr, CC, 0, s);                         // xf
    colnorm_kernel<<<(BB * NN) / 256, 256, 0, s>>>(bufB, xnb, sqc);
    knn_kernel<<<dim3(NN / 64, BB), 256, 0, s>>>(xnb, sqc, rp, idx);
    gather_kernel<<<(BB * CC * NN) / 256, 256, 0, s>>>(bufB, idx, bufA);  // 2C
    conv1(bufA, p.mrw, p.mrb, bufB, 2 * CC, 2 * CC, s);
    inorm(bufB, bufA, nullptr, 2 * CC, 1, s);                     // gelu
    conv1(bufA, p.fc2w, p.fc2b, bufB, 2 * CC, CC, s);
    inorm(bufB, outCur, in, CC, 0, s);                            // + shortcut
}

static void run_ffn(const float* in, const float* w1, const float* b1,
                    const float* w2, const float* b2,
                    float* outCur, float* bufA, float* bufB, hipStream_t s)
{
    conv1(in, w1, b1, bufA, CC, 4 * CC, s);
    inorm(bufA, bufB, nullptr, 4 * CC, 1, s);                     // gelu
    conv1(bufB, w2, b2, bufA, 4 * CC, CC, s);
    inorm(bufA, outCur, in, CC, 0, s);                            // + shortcut
}

extern "C" void kernel_launch(void* const* d_in, const int* in_sizes, int n_in,
                              void* d_out, int out_size, void* d_ws, size_t ws_size,
                              hipStream_t stream)
{
    const float* x  = (const float*)d_in[0];
    const float* rp = (const float*)d_in[1];
    GrapherP g1 = {(const float*)d_in[2],  (const float*)d_in[3],
                   (const float*)d_in[4],  (const float*)d_in[5],
                   (const float*)d_in[6],  (const float*)d_in[7]};
    GrapherP g2 = {(const float*)d_in[8],  (const float*)d_in[9],
                   (const float*)d_in[10], (const float*)d_in[11],
                   (const float*)d_in[12], (const float*)d_in[13]};
    const float* f1w1 = (const float*)d_in[14]; const float* f1b1 = (const float*)d_in[15];
    const float* f1w2 = (const float*)d_in[16]; const float* f1b2 = (const float*)d_in[17];
    const float* f2w1 = (const float*)d_in[18]; const float* f2b1 = (const float*)d_in[19];
    const float* f2w2 = (const float*)d_in[20]; const float* f2b2 = (const float*)d_in[21];
    float* out = (float*)d_out;

    const size_t P  = (size_t)BB * CC * NN;     // 2,408,448 floats
    const size_t P4 = 4 * P;
    float* ws   = (float*)d_ws;
    float* bufA = ws;                 // P4
    float* bufB = bufA + P4;          // P4
    float* xnb  = bufB + P4;          // P
    float* cur0 = xnb + P;            // P
    float* cur1 = cur0 + P;           // P
    float* sqc  = cur1 + P;           // B*N
    int*   idx  = (int*)(sqc + (size_t)BB * NN);   // B*N*9 ints

    // y = grapher1(x)
    run_grapher(x, rp, g1, cur0, bufA, bufB, xnb, sqc, idx, stream);
    // y = ffn1(y)
    run_ffn(cur0, f1w1, f1b1, f1w2, f1b2, cur1, bufA, bufB, stream);
    // y = relu(inorm(y))
    inorm(cur1, cur0, nullptr, CC, 2, stream);
    // y = grapher2(y)
    run_grapher(cur0, rp, g2, cur1, bufA, bufB, xnb, sqc, idx, stream);
    // y = ffn2(y)
    run_ffn(cur1, f2w1, f2b1, f2w2, f2b2, cur0, bufA, bufB, stream);
    // out = x + inorm(y)
    inorm(cur0, out, x, CC, 0, stream);
}

// Round 2
// 2051.285 us; speedup vs baseline: 1.5122x; 1.5122x over previous
//
#include <hip/hip_runtime.h>
#include <math.h>

#define NN 3136      // H*W = 56*56
#define CC 96
#define BB 8
#define KNB 9
#define PARTS 7      // m-range split for knn (7 m-tiles of 64 each)
#define FLT_MAX_ 3.402823466e+38f

// ---------------------------------------------------------------------------
// 1x1 conv as batched GEMM: out[b,o,n] = bias[o] + sum_k w[o*K+k] * in[b,k,n]
// ---------------------------------------------------------------------------
__global__ __launch_bounds__(256) void conv1_kernel(
    const float* __restrict__ in, const float* __restrict__ w,
    const float* __restrict__ bias, float* __restrict__ out, int K, int O)
{
    __shared__ float sW[16][64];   // [kk][o]
    __shared__ float sX[16][64];   // [kk][n]
    const int b  = blockIdx.z;
    const int n0 = blockIdx.x * 64;
    const int o0 = blockIdx.y * 64;
    const int tid = threadIdx.x;
    const int tx = tid & 15, ty = tid >> 4;
    const float* inb = in + (size_t)b * K * NN;

    float acc[4][4] = {{0.f}};

    for (int kb = 0; kb < K; kb += 16) {
        __syncthreads();
        {
            int o  = tid >> 2;
            int k4 = (tid & 3) << 2;
            float4 wv = make_float4(0.f, 0.f, 0.f, 0.f);
            if (o0 + o < O)
                wv = *(const float4*)&w[(size_t)(o0 + o) * K + kb + k4];
            sW[k4 + 0][o] = wv.x; sW[k4 + 1][o] = wv.y;
            sW[k4 + 2][o] = wv.z; sW[k4 + 3][o] = wv.w;
        }
        #pragma unroll
        for (int i = 0; i < 4; i++) {
            int e = tid + i * 256;
            int kk = e >> 6, n2 = e & 63;
            sX[kk][n2] = inb[(size_t)(kb + kk) * NN + n0 + n2];
        }
        __syncthreads();
        #pragma unroll
        for (int kk = 0; kk < 16; kk++) {
            const float4 av = *(const float4*)&sW[kk][ty << 2];
            const float4 xv = *(const float4*)&sX[kk][tx << 2];
            float a_[4] = {av.x, av.y, av.z, av.w};
            float x_[4] = {xv.x, xv.y, xv.z, xv.w};
            #pragma unroll
            for (int i = 0; i < 4; i++)
                #pragma unroll
                for (int j = 0; j < 4; j++)
                    acc[i][j] = fmaf(a_[i], x_[j], acc[i][j]);
        }
    }
    #pragma unroll
    for (int i = 0; i < 4; i++) {
        int o = o0 + (ty << 2) + i;
        if (o < O) {
            float bo = bias[o];
            float4 v = make_float4(acc[i][0] + bo, acc[i][1] + bo,
                                   acc[i][2] + bo, acc[i][3] + bo);
            *(float4*)&out[((size_t)b * O + o) * NN + n0 + (tx << 2)] = v;
        }
    }
}

// ---------------------------------------------------------------------------
// Instance norm over N per (b,c) row; act: 0 none, 1 gelu, 2 relu
// ---------------------------------------------------------------------------
__global__ __launch_bounds__(256) void inorm_kernel(
    const float* __restrict__ in, float* __restrict__ out,
    const float* __restrict__ res, int act)
{
    const int row = blockIdx.x;
    const float* x = in + (size_t)row * NN;
    const int tid = threadIdx.x;

    float v[13];
    float s = 0.f;
    #pragma unroll
    for (int i = 0; i < 13; i++) {
        int idx = tid + i * 256;
        v[i] = (idx < NN) ? x[idx] : 0.f;
        s += v[i];
    }
    __shared__ float red[4];
    #pragma unroll
    for (int off = 32; off > 0; off >>= 1) s += __shfl_down(s, off);
    if ((tid & 63) == 0) red[tid >> 6] = s;
    __syncthreads();
    const float mean = (red[0] + red[1] + red[2] + red[3]) * (1.f / (float)NN);

    float s2 = 0.f;
    #pragma unroll
    for (int i = 0; i < 13; i++) {
        int idx = tid + i * 256;
        if (idx < NN) { float d = v[i] - mean; s2 = fmaf(d, d, s2); }
    }
    #pragma unroll
    for (int off = 32; off > 0; off >>= 1) s2 += __shfl_down(s2, off);
    __syncthreads();
    if ((tid & 63) == 0) red[tid >> 6] = s2;
    __syncthreads();
    const float var = (red[0] + red[1] + red[2] + red[3]) * (1.f / (float)NN);
    const float rs = rsqrtf(var + 1e-5f);

    float* o = out + (size_t)row * NN;
    const float* rr = res ? (res + (size_t)row * NN) : nullptr;
    #pragma unroll
    for (int i = 0; i < 13; i++) {
        int idx = tid + i * 256;
        if (idx < NN) {
            float y = (v[i] - mean) * rs;
            if (act == 1)      y = 0.5f * y * (1.f + erff(y * 0.70710678118654752f));
            else if (act == 2) y = fmaxf(y, 0.f);
            if (rr) y += rr[idx];
            o[idx] = y;
        }
    }
}

// ---------------------------------------------------------------------------
// Column (channel) L2-normalize + sq[b,n] = sum_c xn^2
// ---------------------------------------------------------------------------
__global__ __launch_bounds__(256) void colnorm_kernel(
    const float* __restrict__ xf, float* __restrict__ xn,
    float* __restrict__ sqc)
{
    const int g = blockIdx.x * 256 + threadIdx.x;   // over B*N
    const int b = g / NN;
    const int n = g - b * NN;
    const float* p = xf + (size_t)b * CC * NN + n;
    float* q = xn + (size_t)b * CC * NN + n;

    float s = 0.f;
    for (int c = 0; c < CC; c++) { float t = p[(size_t)c * NN]; s = fmaf(t, t, s); }
    const float den = fmaxf(sqrtf(s), 1e-12f);

    float sq = 0.f;
    for (int c = 0; c < CC; c++) {
        float t = p[(size_t)c * NN] / den;
        q[(size_t)c * NN] = t;
        sq = fmaf(t, t, sq);
    }
    sqc[g] = sq;
}

// ---------------------------------------------------------------------------
// top-9 register insertion helpers (fully unrolled -> stays in VGPRs)
// ---------------------------------------------------------------------------
__device__ __forceinline__ void ins9(float (&dv)[9], int (&di)[9], float d, int m)
{
    if (d < dv[8]) {
        dv[8] = d; di[8] = m;
        #pragma unroll
        for (int j = 8; j > 0; --j) {
            if (dv[j] < dv[j - 1]) {
                float tv = dv[j]; dv[j] = dv[j - 1]; dv[j - 1] = tv;
                int   ti = di[j]; di[j] = di[j - 1]; di[j - 1] = ti;
            }
        }
    }
}
__device__ __forceinline__ void ins9tb(float (&dv)[9], int (&di)[9], float d, int m)
{
    if (d < dv[8] || (d == dv[8] && m < di[8])) {
        dv[8] = d; di[8] = m;
        #pragma unroll
        for (int j = 8; j > 0; --j) {
            bool sw = (dv[j] < dv[j - 1]) ||
                      (dv[j] == dv[j - 1] && di[j] < di[j - 1]);
            if (sw) {
                float tv = dv[j]; dv[j] = dv[j - 1]; dv[j - 1] = tv;
                int   ti = di[j]; di[j] = di[j - 1]; di[j - 1] = ti;
            }
        }
    }
}

// ---------------------------------------------------------------------------
// kNN stage 1: per (b, 64-row tile, m-part) compute distances and per-row
// top-9 within the part. 256 threads, 2x8 micro-tile (2 lists/thread).
// d[m] = sq[m] - 2*dot(xn[:,r], xn[:,m]) + rp[r,m]   (sq[r] dropped)
// Partials out: pv/pi [(b*NN + r)*PARTS + part][9]
// ---------------------------------------------------------------------------
__global__ __launch_bounds__(256, 2) void knn_kernel(
    const float* __restrict__ xn, const float* __restrict__ sqc,
    const float* __restrict__ rp, float* __restrict__ pv, int* __restrict__ pi)
{
    __shared__ float shR[CC * 64];    // [c][r]   24 KB, persistent
    __shared__ float shC[48 * 64];    // [c][m]   12 KB, chunked over c
    const int b    = blockIdx.z;
    const int part = blockIdx.y;
    const int r0   = blockIdx.x * 64;
    const int tid  = threadIdx.x;
    const int tx = tid & 7;           // 8 col groups of 8
    const int ty = tid >> 3;          // 32 row groups of 2
    const float* xb = xn + (size_t)b * CC * NN;

    // stage 64-row slab of xn (float4, coalesced)
    #pragma unroll
    for (int i = 0; i < 6; i++) {
        int idx = tid + i * 256;              // < 1536 float4s
        int c = idx >> 4, r4 = (idx & 15) << 2;
        *(float4*)&shR[c * 64 + r4] = *(const float4*)&xb[(size_t)c * NN + r0 + r4];
    }

    float dv0[9], dv1[9]; int di0[9], di1[9];
    #pragma unroll
    for (int j = 0; j < 9; j++) { dv0[j] = dv1[j] = FLT_MAX_; di0[j] = di1[j] = 0x7fffffff; }

    const int rA = r0 + ty * 2;

    for (int mt = 0; mt < PARTS; mt++) {
        const int m0 = (part * PARTS + mt) * 64;
        float acc0[8] = {0.f, 0.f, 0.f, 0.f, 0.f, 0.f, 0.f, 0.f};
        float acc1[8] = {0.f, 0.f, 0.f, 0.f, 0.f, 0.f, 0.f, 0.f};

        for (int cb = 0; cb < CC; cb += 48) {
            __syncthreads();
            #pragma unroll
            for (int i = 0; i < 3; i++) {
                int idx = tid + i * 256;          // < 768 float4s
                int c = idx >> 4, m4 = (idx & 15) << 2;
                *(float4*)&shC[c * 64 + m4] =
                    *(const float4*)&xb[(size_t)(cb + c) * NN + m0 + m4];
            }
            __syncthreads();
            #pragma unroll 4
            for (int c = 0; c < 48; c++) {
                const float2 rv = *(const float2*)&shR[(cb + c) * 64 + ty * 2];
                const float4 c0 = *(const float4*)&shC[c * 64 + tx * 8];
                const float4 c1 = *(const float4*)&shC[c * 64 + tx * 8 + 4];
                acc0[0] = fmaf(rv.x, c0.x, acc0[0]);
                acc0[1] = fmaf(rv.x, c0.y, acc0[1]);
                acc0[2] = fmaf(rv.x, c0.z, acc0[2]);
                acc0[3] = fmaf(rv.x, c0.w, acc0[3]);
                acc0[4] = fmaf(rv.x, c1.x, acc0[4]);
                acc0[5] = fmaf(rv.x, c1.y, acc0[5]);
                acc0[6] = fmaf(rv.x, c1.z, acc0[6]);
                acc0[7] = fmaf(rv.x, c1.w, acc0[7]);
                acc1[0] = fmaf(rv.y, c0.x, acc1[0]);
                acc1[1] = fmaf(rv.y, c0.y, acc1[1]);
                acc1[2] = fmaf(rv.y, c0.z, acc1[2]);
                acc1[3] = fmaf(rv.y, c0.w, acc1[3]);
                acc1[4] = fmaf(rv.y, c1.x, acc1[4]);
                acc1[5] = fmaf(rv.y, c1.y, acc1[5]);
                acc1[6] = fmaf(rv.y, c1.z, acc1[6]);
                acc1[7] = fmaf(rv.y, c1.w, acc1[7]);
            }
        }

        // epilogue: distances + top-9 insertion
        const float4 s0 = *(const float4*)&sqc[(size_t)b * NN + m0 + tx * 8];
        const float4 s1 = *(const float4*)&sqc[(size_t)b * NN + m0 + tx * 8 + 4];
        const float4 a0 = *(const float4*)&rp[(size_t)rA * NN + m0 + tx * 8];
        const float4 a1 = *(const float4*)&rp[(size_t)rA * NN + m0 + tx * 8 + 4];
        const float4 b0 = *(const float4*)&rp[(size_t)(rA + 1) * NN + m0 + tx * 8];
        const float4 b1 = *(const float4*)&rp[(size_t)(rA + 1) * NN + m0 + tx * 8 + 4];
        const float sq_[8] = {s0.x, s0.y, s0.z, s0.w, s1.x, s1.y, s1.z, s1.w};
        const float rA_[8] = {a0.x, a0.y, a0.z, a0.w, a1.x, a1.y, a1.z, a1.w};
        const float rB_[8] = {b0.x, b0.y, b0.z, b0.w, b1.x, b1.y, b1.z, b1.w};
        #pragma unroll
        for (int j = 0; j < 8; j++) {
            const int m = m0 + tx * 8 + j;
            ins9(dv0, di0, fmaf(-2.f, acc0[j], sq_[j] + rA_[j]), m);
            ins9(dv1, di1, fmaf(-2.f, acc1[j], sq_[j] + rB_[j]), m);
        }
    }

    // merge the 8 tx-lists per row through LDS; 2 passes (row 0/1 of thread)
    float* mv = shR;             // 2304 floats needed, have 6144
    int*   mi = (int*)shC;       // 2304 ints needed, have 3072
    #pragma unroll
    for (int i = 0; i < 2; i++) {
        __syncthreads();
        #pragma unroll
        for (int j = 0; j < 9; j++) {
            mv[tid * 9 + j] = i ? dv1[j] : dv0[j];
            mi[tid * 9 + j] = i ? di1[j] : di0[j];
        }
        __syncthreads();
        if (tid < 32) {
            float bv[9]; int bi[9];
            #pragma unroll
            for (int j = 0; j < 9; j++) { bv[j] = FLT_MAX_; bi[j] = 0x7fffffff; }
            for (int t = 0; t < 8; t++) {
                const int base = (tid * 8 + t) * 9;
                #pragma unroll
                for (int j = 0; j < 9; j++)
                    ins9tb(bv, bi, mv[base + j], mi[base + j]);
            }
            const int r = r0 + tid * 2 + i;
            const size_t o = ((size_t)(b * NN + r) * PARTS + part) * KNB;
            #pragma unroll
            for (int j = 0; j < 9; j++) { pv[o + j] = bv[j]; pi[o + j] = bi[j]; }
        }
    }
}

// ---------------------------------------------------------------------------
// kNN stage 2: merge PARTS partial lists per (b,n) -> final nn_idx
// ---------------------------------------------------------------------------
__global__ __launch_bounds__(256) void knn_merge_kernel(
    const float* __restrict__ pv, const int* __restrict__ pi,
    int* __restrict__ nn_idx)
{
    const int g = blockIdx.x * 256 + threadIdx.x;   // over B*N
    if (g >= BB * NN) return;
    float bv[9]; int bi[9];
    #pragma unroll
    for (int j = 0; j < 9; j++) { bv[j] = FLT_MAX_; bi[j] = 0x7fffffff; }
    const float* v = pv + (size_t)g * PARTS * KNB;
    const int*   w = pi + (size_t)g * PARTS * KNB;
    for (int p = 0; p < PARTS; p++)
        #pragma unroll
        for (int j = 0; j < 9; j++)
            ins9tb(bv, bi, v[p * KNB + j], w[p * KNB + j]);
    #pragma unroll
    for (int j = 0; j < 9; j++) nn_idx[(size_t)g * KNB + j] = bi[j];
}

// ---------------------------------------------------------------------------
// Max-relative gather + channel interleave
// ---------------------------------------------------------------------------
__global__ __launch_bounds__(256) void gather_kernel(
    const float* __restrict__ xf, const int* __restrict__ nn_idx,
    float* __restrict__ y)
{
    const size_t g = (size_t)blockIdx.x * 256 + threadIdx.x;   // over B*C*N
    const int n  = (int)(g % NN);
    const int bc = (int)(g / NN);
    const int c  = bc % CC;
    const int b  = bc / CC;
    const float* row = xf + (size_t)(b * CC + c) * NN;
    const float xi = row[n];
    const int* id = nn_idx + ((size_t)b * NN + n) * KNB;
    float mx = -FLT_MAX_;
    #pragma unroll
    for (int k = 0; k < KNB; k++) mx = fmaxf(mx, row[id[k]] - xi);
    float* o = y + ((size_t)b * 2 * CC + 2 * c) * NN + n;
    o[0]  = xi;
    o[NN] = mx;
}

// ---------------------------------------------------------------------------
// Host-side orchestration
// ---------------------------------------------------------------------------
static void conv1(const float* in, const float* w, const float* b, float* out,
                  int K, int O, hipStream_t s)
{
    dim3 grid(NN / 64, (O + 63) / 64, BB);
    conv1_kernel<<<grid, 256, 0, s>>>(in, w, b, out, K, O);
}
static void inorm(const float* in, float* out, const float* res, int ch, int act,
                  hipStream_t s)
{
    inorm_kernel<<<BB * ch, 256, 0, s>>>(in, out, res, act);
}

struct GrapherP {
    const float *fc1w, *fc1b, *mrw, *mrb, *fc2w, *fc2b;
};

static void run_grapher(const float* in, const float* rp, const GrapherP& p,
                        float* outCur, float* bufA, float* bufB, float* xnb,
                        float* sqc, int* idx, hipStream_t s)
{
    conv1(in, p.fc1w, p.fc1b, bufA, CC, CC, s);
    inorm(bufA, bufB, nullptr, CC, 0, s);                         // xf
    colnorm_kernel<<<(BB * NN) / 256, 256, 0, s>>>(bufB, xnb, sqc);
    // partial-list scratch lives in bufA (free until gather writes it)
    float* pv = bufA;
    int*   pi = (int*)(bufA + (size_t)BB * NN * PARTS * KNB);
    knn_kernel<<<dim3(NN / 64, PARTS, BB), 256, 0, s>>>(xnb, sqc, rp, pv, pi);
    knn_merge_kernel<<<(BB * NN + 255) / 256, 256, 0, s>>>(pv, pi, idx);
    gather_kernel<<<(BB * CC * NN) / 256, 256, 0, s>>>(bufB, idx, bufA);  // 2C
    conv1(bufA, p.mrw, p.mrb, bufB, 2 * CC, 2 * CC, s);
    inorm(bufB, bufA, nullptr, 2 * CC, 1, s);                     // gelu
    conv1(bufA, p.fc2w, p.fc2b, bufB, 2 * CC, CC, s);
    inorm(bufB, outCur, in, CC, 0, s);                            // + shortcut
}

static void run_ffn(const float* in, const float* w1, const float* b1,
                    const float* w2, const float* b2,
                    float* outCur, float* bufA, float* bufB, hipStream_t s)
{
    conv1(in, w1, b1, bufA, CC, 4 * CC, s);
    inorm(bufA, bufB, nullptr, 4 * CC, 1, s);                     // gelu
    conv1(bufB, w2, b2, bufA, 2 * CC * 2, CC, s);
    inorm(bufA, outCur, in, CC, 0, s);                            // + shortcut
}

extern "C" void kernel_launch(void* const* d_in, const int* in_sizes, int n_in,
                              void* d_out, int out_size, void* d_ws, size_t ws_size,
                              hipStream_t stream)
{
    const float* x  = (const float*)d_in[0];
    const float* rp = (const float*)d_in[1];
    GrapherP g1 = {(const float*)d_in[2],  (const float*)d_in[3],
                   (const float*)d_in[4],  (const float*)d_in[5],
                   (const float*)d_in[6],  (const float*)d_in[7]};
    GrapherP g2 = {(const float*)d_in[8],  (const float*)d_in[9],
                   (const float*)d_in[10], (const float*)d_in[11],
                   (const float*)d_in[12], (const float*)d_in[13]};
    const float* f1w1 = (const float*)d_in[14]; const float* f1b1 = (const float*)d_in[15];
    const float* f1w2 = (const float*)d_in[16]; const float* f1b2 = (const float*)d_in[17];
    const float* f2w1 = (const float*)d_in[18]; const float* f2b1 = (const float*)d_in[19];
    const float* f2w2 = (const float*)d_in[20]; const float* f2b2 = (const float*)d_in[21];
    float* out = (float*)d_out;

    const size_t P  = (size_t)BB * CC * NN;     // 2,408,448 floats
    const size_t P4 = 4 * P;
    float* ws   = (float*)d_ws;
    float* bufA = ws;                 // P4
    float* bufB = bufA + P4;          // P4
    float* xnb  = bufB + P4;          // P
    float* cur0 = xnb + P;            // P
    float* cur1 = cur0 + P;           // P
    float* sqc  = cur1 + P;           // B*N
    int*   idx  = (int*)(sqc + (size_t)BB * NN);   // B*N*9 ints

    run_grapher(x, rp, g1, cur0, bufA, bufB, xnb, sqc, idx, stream);
    run_ffn(cur0, f1w1, f1b1, f1w2, f1b2, cur1, bufA, bufB, stream);
    inorm(cur1, cur0, nullptr, CC, 2, stream);
    run_grapher(cur0, rp, g2, cur1, bufA, bufB, xnb, sqc, idx, stream);
    run_ffn(cur1, f2w1, f2b1, f2w2, f2b2, cur0, bufA, bufB, stream);
    inorm(cur0, out, x, CC, 0, stream);
}